// Round 1
// baseline (268.860 us; speedup 1.0000x reference)
//
#include <hip/hip_runtime.h>
#include <math.h>

// Problem constants (fixed shapes from reference)
#define IN_CH   8
#define OUT_CH  16
#define DIM     32
#define PDIM    34          // padded (pad=1 each side)
#define NBASES  8           // GRID_SIZE + SPLINE_ORDER
#define NF      216         // IN_CH * 27
#define LTOT    32768       // 32^3

// knot j of the (uniform) extended grid: (j-3)*h + lo, h=0.4, lo=-1
__device__ __forceinline__ float knot(int j) {
    return (float)(j - 3) * 0.4f + (-1.0f);
}

// Cox-de Boor recursion, exactly mirroring the reference (order 3, 12 knots).
// Produces the 8 final basis values in b[0..7].
__device__ __forceinline__ void eval_bases(float v, float b[11]) {
    #pragma unroll
    for (int j = 0; j < 11; ++j)
        b[j] = (v >= knot(j) && v < knot(j + 1)) ? 1.0f : 0.0f;
    #pragma unroll
    for (int k = 1; k <= 3; ++k) {
        #pragma unroll
        for (int j = 0; j + k < 11; ++j) {
            float denl = knot(j + k)     - knot(j);
            float denr = knot(j + k + 1) - knot(j + 1);
            b[j] = (v - knot(j)) / denl * b[j]
                 + (knot(j + k + 1) - v) / denr * b[j + 1];
        }
    }
}

__device__ __forceinline__ float silu(float v) {
    return v / (1.0f + expf(-v));
}

// ---------------- Stage 1: per padded element, [silu, B0..B7] ----------------
__global__ void precompute_kernel(const float* __restrict__ x,
                                  float* __restrict__ S,   // [8*34^3]
                                  float* __restrict__ B) { // [8*34^3][8]
    int idx = blockIdx.x * blockDim.x + threadIdx.x;
    const int total = IN_CH * PDIM * PDIM * PDIM;
    if (idx >= total) return;
    int xp = idx % PDIM;
    int t  = idx / PDIM;
    int yp = t % PDIM; t /= PDIM;
    int zp = t % PDIM;
    int c  = t / PDIM;
    float v = 0.0f;
    if (xp >= 1 && xp <= DIM && yp >= 1 && yp <= DIM && zp >= 1 && zp <= DIM) {
        v = x[((c * DIM + (zp - 1)) * DIM + (yp - 1)) * DIM + (xp - 1)];
    }
    float b[11];
    eval_bases(v, b);
    S[idx] = silu(v);
    float4* Bp = (float4*)(B + (size_t)idx * NBASES);
    Bp[0] = make_float4(b[0], b[1], b[2], b[3]);
    Bp[1] = make_float4(b[4], b[5], b[6], b[7]);
}

// --------- Stage 1b: combined weights Wc[i][o][12] (t0=base, t1..8=spline) ---
__global__ void prep_weights_kernel(const float* __restrict__ bw,   // [16][216]
                                    const float* __restrict__ sw,   // [16][216][8]
                                    const float* __restrict__ sc,   // [16][216]
                                    float* __restrict__ Wc) {       // [216][16][12]
    int idx = blockIdx.x * blockDim.x + threadIdx.x;
    if (idx >= OUT_CH * NF) return;
    int o = idx / NF, i = idx % NF;
    float* w = Wc + ((size_t)i * OUT_CH + o) * 12;
    int wi = o * NF + i;
    w[0] = bw[wi];
    float scale = sc[wi];
    #pragma unroll
    for (int j = 0; j < NBASES; ++j) w[1 + j] = sw[(size_t)wi * NBASES + j] * scale;
    w[9] = 0.0f; w[10] = 0.0f; w[11] = 0.0f;
}

// ---------------- Stage 2: the 72ch -> 16ch 3x3x3 conv ----------------------
// Grid: 1024 blocks x 64 threads. block b: og = b&1 (which 8 output chans),
// p = (b>>1)*64 + tid (output position).
__global__ __launch_bounds__(64) void conv_kernel(const float* __restrict__ S,
                                                  const float* __restrict__ B,
                                                  const float* __restrict__ Wc,
                                                  float* __restrict__ out) {
    int blk = blockIdx.x;
    int og  = blk & 1;
    int p   = (blk >> 1) * 64 + threadIdx.x;
    int xo = p & 31;
    int yo = (p >> 5) & 31;
    int zo = p >> 10;
    float acc[8];
    #pragma unroll
    for (int o = 0; o < 8; ++o) acc[o] = 0.0f;

    for (int c = 0; c < IN_CH; ++c) {
        for (int kd = 0; kd < 3; ++kd) {
            for (int kh = 0; kh < 3; ++kh) {
                #pragma unroll
                for (int kw = 0; kw < 3; ++kw) {
                    int zi = zo + kd, yi = yo + kh, xi = xo + kw; // padded coords
                    size_t u = (((size_t)c * PDIM + zi) * PDIM + yi) * PDIM + xi;
                    float s  = S[u];
                    float4 b0 = *(const float4*)(B + u * NBASES);
                    float4 b1 = *(const float4*)(B + u * NBASES + 4);
                    int i = c * 27 + kd * 9 + kh * 3 + kw;
                    const float* w = Wc + ((size_t)i * OUT_CH + og * 8) * 12;
                    #pragma unroll
                    for (int o = 0; o < 8; ++o) {
                        float4 w0 = *(const float4*)(w + o * 12);
                        float4 w1 = *(const float4*)(w + o * 12 + 4);
                        float  w8 = w[o * 12 + 8];
                        acc[o] += s    * w0.x + b0.x * w0.y + b0.y * w0.z + b0.z * w0.w
                                + b0.w * w1.x + b1.x * w1.y + b1.y * w1.z + b1.z * w1.w
                                + b1.w * w8;
                    }
                }
            }
        }
    }
    #pragma unroll
    for (int o = 0; o < 8; ++o)
        out[(size_t)(og * 8 + o) * LTOT + p] = acc[o];
}

// ---------------- Fallback: fully fused (no workspace needed) ---------------
__global__ __launch_bounds__(64) void fused_kernel(const float* __restrict__ x,
                                                   const float* __restrict__ bw,
                                                   const float* __restrict__ sw,
                                                   const float* __restrict__ sc,
                                                   float* __restrict__ out) {
    int p = blockIdx.x * 64 + threadIdx.x;
    int xo = p & 31;
    int yo = (p >> 5) & 31;
    int zo = p >> 10;
    float acc[OUT_CH];
    #pragma unroll
    for (int o = 0; o < OUT_CH; ++o) acc[o] = 0.0f;

    for (int c = 0; c < IN_CH; ++c) {
        for (int kd = 0; kd < 3; ++kd) {
            for (int kh = 0; kh < 3; ++kh) {
                for (int kw = 0; kw < 3; ++kw) {
                    int zi = zo + kd - 1, yi = yo + kh - 1, xi = xo + kw - 1;
                    float v = 0.0f;
                    if (zi >= 0 && zi < DIM && yi >= 0 && yi < DIM && xi >= 0 && xi < DIM)
                        v = x[((c * DIM + zi) * DIM + yi) * DIM + xi];
                    float b[11];
                    eval_bases(v, b);
                    float s = silu(v);
                    int i = c * 27 + kd * 9 + kh * 3 + kw;
                    #pragma unroll
                    for (int o = 0; o < OUT_CH; ++o) {
                        int wi = o * NF + i;
                        float dot = 0.0f;
                        #pragma unroll
                        for (int j = 0; j < NBASES; ++j)
                            dot += b[j] * sw[(size_t)wi * NBASES + j];
                        acc[o] += s * bw[wi] + sc[wi] * dot;
                    }
                }
            }
        }
    }
    #pragma unroll
    for (int o = 0; o < OUT_CH; ++o)
        out[(size_t)o * LTOT + p] = acc[o];
}

extern "C" void kernel_launch(void* const* d_in, const int* in_sizes, int n_in,
                              void* d_out, int out_size, void* d_ws, size_t ws_size,
                              hipStream_t stream) {
    const float* x  = (const float*)d_in[0];
    const float* bw = (const float*)d_in[1];
    const float* sw = (const float*)d_in[2];
    const float* sc = (const float*)d_in[3];
    float* out = (float*)d_out;

    const size_t S_bytes = (size_t)IN_CH * PDIM * PDIM * PDIM * 4;            // 1,257,728
    const size_t B_bytes = (size_t)IN_CH * PDIM * PDIM * PDIM * NBASES * 4;   // 10,061,824
    const size_t W_bytes = (size_t)NF * OUT_CH * 12 * 4;                      // 165,888
    const size_t S_off = 0;
    const size_t B_off = S_off + S_bytes;          // 16B aligned
    const size_t W_off = B_off + B_bytes;          // 16B aligned
    const size_t need  = W_off + W_bytes;

    if (ws_size >= need) {
        float* S  = (float*)((char*)d_ws + S_off);
        float* B  = (float*)((char*)d_ws + B_off);
        float* Wc = (float*)((char*)d_ws + W_off);
        const int total1 = IN_CH * PDIM * PDIM * PDIM;
        precompute_kernel<<<(total1 + 255) / 256, 256, 0, stream>>>(x, S, B);
        prep_weights_kernel<<<(OUT_CH * NF + 255) / 256, 256, 0, stream>>>(bw, sw, sc, Wc);
        conv_kernel<<<1024, 64, 0, stream>>>(S, B, Wc, out);
    } else {
        fused_kernel<<<512, 64, 0, stream>>>(x, bw, sw, sc, out);
    }
}

// Round 2
// 198.753 us; speedup vs baseline: 1.3527x; 1.3527x over previous
//
#include <hip/hip_runtime.h>
#include <math.h>

// Problem constants (fixed shapes from reference)
#define IN_CH   8
#define OUT_CH  16
#define DIM     32
#define PDIM    34          // padded (pad=1 each side)
#define NBASES  8           // GRID_SIZE + SPLINE_ORDER
#define NF      216         // IN_CH * 27
#define LTOT    32768       // 32^3

// knot j of the (uniform) extended grid: (j-3)*h + lo, h=0.4, lo=-1
__device__ __forceinline__ float knot(int j) {
    return (float)(j - 3) * 0.4f + (-1.0f);
}

// Cox-de Boor recursion, exactly mirroring the reference (order 3, 12 knots).
// Denominators are compile-time constants (uniform grid) -> folded to muls.
__device__ __forceinline__ void eval_bases(float v, float b[11]) {
    #pragma unroll
    for (int j = 0; j < 11; ++j)
        b[j] = (v >= knot(j) && v < knot(j + 1)) ? 1.0f : 0.0f;
    #pragma unroll
    for (int k = 1; k <= 3; ++k) {
        #pragma unroll
        for (int j = 0; j + k < 11; ++j) {
            float denl = knot(j + k)     - knot(j);
            float denr = knot(j + k + 1) - knot(j + 1);
            b[j] = (v - knot(j)) / denl * b[j]
                 + (knot(j + k + 1) - v) / denr * b[j + 1];
        }
    }
}

__device__ __forceinline__ float silu(float v) {
    return v / (1.0f + expf(-v));
}

// ---------------- Stage 1: per padded element, [silu, B0..B7] ----------------
__global__ void precompute_kernel(const float* __restrict__ x,
                                  float* __restrict__ S,   // [8*34^3]
                                  float* __restrict__ B) { // [8*34^3][8]
    int idx = blockIdx.x * blockDim.x + threadIdx.x;
    const int total = IN_CH * PDIM * PDIM * PDIM;
    if (idx >= total) return;
    int xp = idx % PDIM;
    int t  = idx / PDIM;
    int yp = t % PDIM; t /= PDIM;
    int zp = t % PDIM;
    int c  = t / PDIM;
    float v = 0.0f;
    if (xp >= 1 && xp <= DIM && yp >= 1 && yp <= DIM && zp >= 1 && zp <= DIM) {
        v = x[((c * DIM + (zp - 1)) * DIM + (yp - 1)) * DIM + (xp - 1)];
    }
    float b[11];
    eval_bases(v, b);
    S[idx] = silu(v);
    float4* Bp = (float4*)(B + (size_t)idx * NBASES);
    Bp[0] = make_float4(b[0], b[1], b[2], b[3]);
    Bp[1] = make_float4(b[4], b[5], b[6], b[7]);
}

// --------- Stage 1b: combined weights Wc[i][o][12] (t0=base, t1..8=spline) ---
__global__ void prep_weights_kernel(const float* __restrict__ bw,   // [16][216]
                                    const float* __restrict__ sw,   // [16][216][8]
                                    const float* __restrict__ sc,   // [16][216]
                                    float* __restrict__ Wc) {       // [216][16][12]
    int idx = blockIdx.x * blockDim.x + threadIdx.x;
    if (idx >= OUT_CH * NF) return;
    int o = idx / NF, i = idx % NF;
    float* w = Wc + ((size_t)i * OUT_CH + o) * 12;
    int wi = o * NF + i;
    w[0] = bw[wi];
    float scale = sc[wi];
    #pragma unroll
    for (int j = 0; j < NBASES; ++j) w[1 + j] = sw[(size_t)wi * NBASES + j] * scale;
    w[9] = 0.0f; w[10] = 0.0f; w[11] = 0.0f;
}

// ---------------- Stage 2: the 72ch -> 16ch 3x3x3 conv ----------------------
// Grid: 2048 blocks x 64 threads. block b: split = b&3 (which 2 input chans),
// p = (b>>2)*64 + tid (output position). All 16 outputs per thread; weight
// addresses are wave-uniform (loop vars + blockIdx only) -> scalar loads.
// Partial results combined with fp32 atomicAdd into memset-zeroed out.
__global__ __launch_bounds__(64) void conv_kernel(const float* __restrict__ S,
                                                  const float* __restrict__ B,
                                                  const float* __restrict__ Wc,
                                                  float* __restrict__ out) {
    int blk   = blockIdx.x;
    int split = blk & 3;
    int p     = (blk >> 2) * 64 + threadIdx.x;
    int xo = p & 31;
    int yo = (p >> 5) & 31;
    int zo = p >> 10;
    float acc[OUT_CH];
    #pragma unroll
    for (int o = 0; o < OUT_CH; ++o) acc[o] = 0.0f;

    for (int cc = 0; cc < 2; ++cc) {
        int c = split * 2 + cc;
        for (int kd = 0; kd < 3; ++kd) {
            for (int kh = 0; kh < 3; ++kh) {
                size_t ubase = (((size_t)c * PDIM + (zo + kd)) * PDIM + (yo + kh)) * PDIM + xo;
                int    ibase = ((c * 3 + kd) * 3 + kh) * 3;
                #pragma unroll
                for (int kw = 0; kw < 3; ++kw) {
                    size_t u = ubase + kw;
                    float  s  = S[u];
                    float4 b0 = *(const float4*)(B + u * NBASES);
                    float4 b1 = *(const float4*)(B + u * NBASES + 4);
                    const float* w = Wc + (size_t)(ibase + kw) * OUT_CH * 12;
                    #pragma unroll
                    for (int o = 0; o < OUT_CH; ++o) {
                        const float* wo = w + o * 12;   // uniform -> s_load
                        acc[o] += s    * wo[0] + b0.x * wo[1] + b0.y * wo[2]
                                + b0.z * wo[3] + b0.w * wo[4] + b1.x * wo[5]
                                + b1.y * wo[6] + b1.z * wo[7] + b1.w * wo[8];
                    }
                }
            }
        }
    }
    #pragma unroll
    for (int o = 0; o < OUT_CH; ++o)
        atomicAdd(&out[(size_t)o * LTOT + p], acc[o]);
}

// ---------------- Fallback: fully fused (no workspace needed) ---------------
__global__ __launch_bounds__(64) void fused_kernel(const float* __restrict__ x,
                                                   const float* __restrict__ bw,
                                                   const float* __restrict__ sw,
                                                   const float* __restrict__ sc,
                                                   float* __restrict__ out) {
    int p = blockIdx.x * 64 + threadIdx.x;
    int xo = p & 31;
    int yo = (p >> 5) & 31;
    int zo = p >> 10;
    float acc[OUT_CH];
    #pragma unroll
    for (int o = 0; o < OUT_CH; ++o) acc[o] = 0.0f;

    for (int c = 0; c < IN_CH; ++c) {
        for (int kd = 0; kd < 3; ++kd) {
            for (int kh = 0; kh < 3; ++kh) {
                for (int kw = 0; kw < 3; ++kw) {
                    int zi = zo + kd - 1, yi = yo + kh - 1, xi = xo + kw - 1;
                    float v = 0.0f;
                    if (zi >= 0 && zi < DIM && yi >= 0 && yi < DIM && xi >= 0 && xi < DIM)
                        v = x[((c * DIM + zi) * DIM + yi) * DIM + xi];
                    float b[11];
                    eval_bases(v, b);
                    float s = silu(v);
                    int i = c * 27 + kd * 9 + kh * 3 + kw;
                    #pragma unroll
                    for (int o = 0; o < OUT_CH; ++o) {
                        int wi = o * NF + i;
                        float dot = 0.0f;
                        #pragma unroll
                        for (int j = 0; j < NBASES; ++j)
                            dot += b[j] * sw[(size_t)wi * NBASES + j];
                        acc[o] += s * bw[wi] + sc[wi] * dot;
                    }
                }
            }
        }
    }
    #pragma unroll
    for (int o = 0; o < OUT_CH; ++o)
        out[(size_t)o * LTOT + p] = acc[o];
}

extern "C" void kernel_launch(void* const* d_in, const int* in_sizes, int n_in,
                              void* d_out, int out_size, void* d_ws, size_t ws_size,
                              hipStream_t stream) {
    const float* x  = (const float*)d_in[0];
    const float* bw = (const float*)d_in[1];
    const float* sw = (const float*)d_in[2];
    const float* sc = (const float*)d_in[3];
    float* out = (float*)d_out;

    const size_t S_bytes = (size_t)IN_CH * PDIM * PDIM * PDIM * 4;            // 1,257,728
    const size_t B_bytes = (size_t)IN_CH * PDIM * PDIM * PDIM * NBASES * 4;   // 10,061,824
    const size_t W_bytes = (size_t)NF * OUT_CH * 12 * 4;                      // 165,888
    const size_t S_off = 0;
    const size_t B_off = S_off + S_bytes;          // 16B aligned
    const size_t W_off = B_off + B_bytes;          // 16B aligned
    const size_t need  = W_off + W_bytes;

    if (ws_size >= need) {
        float* S  = (float*)((char*)d_ws + S_off);
        float* B  = (float*)((char*)d_ws + B_off);
        float* Wc = (float*)((char*)d_ws + W_off);
        const int total1 = IN_CH * PDIM * PDIM * PDIM;
        precompute_kernel<<<(total1 + 255) / 256, 256, 0, stream>>>(x, S, B);
        prep_weights_kernel<<<(OUT_CH * NF + 255) / 256, 256, 0, stream>>>(bw, sw, sc, Wc);
        hipMemsetAsync(d_out, 0, (size_t)out_size * sizeof(float), stream);
        conv_kernel<<<2048, 64, 0, stream>>>(S, B, Wc, out);
    } else {
        fused_kernel<<<512, 64, 0, stream>>>(x, bw, sw, sc, out);
    }
}

// Round 3
// 87.161 us; speedup vs baseline: 3.0846x; 2.2803x over previous
//
#include <hip/hip_runtime.h>
#include <math.h>

// Problem constants (fixed shapes from reference)
#define IN_CH   8
#define OUT_CH  16
#define DIM     32
#define PDIM    34          // padded (pad=1 each side)
#define NBASES  8           // GRID_SIZE + SPLINE_ORDER
#define NF      216         // IN_CH * 27
#define LTOT    32768       // 32^3
#define TPAD    12          // 9 real values (silu + 8 bases) padded to 12
#define KVOX    96          // 8 channels * TPAD halves per voxel
#define NVOX    (PDIM*PDIM*PDIM)

typedef _Float16 half8 __attribute__((ext_vector_type(8)));
typedef float    f32x4 __attribute__((ext_vector_type(4)));

// knot j of the (uniform) extended grid: (j-3)*h + lo, h=0.4, lo=-1
__device__ __forceinline__ float knot(int j) {
    return (float)(j - 3) * 0.4f + (-1.0f);
}

// Cox-de Boor recursion, exactly mirroring the reference (order 3, 12 knots).
__device__ __forceinline__ void eval_bases(float v, float b[11]) {
    #pragma unroll
    for (int j = 0; j < 11; ++j)
        b[j] = (v >= knot(j) && v < knot(j + 1)) ? 1.0f : 0.0f;
    #pragma unroll
    for (int k = 1; k <= 3; ++k) {
        #pragma unroll
        for (int j = 0; j + k < 11; ++j) {
            float denl = knot(j + k)     - knot(j);
            float denr = knot(j + k + 1) - knot(j + 1);
            b[j] = (v - knot(j)) / denl * b[j]
                 + (knot(j + k + 1) - v) / denr * b[j + 1];
        }
    }
}

__device__ __forceinline__ float silu(float v) {
    return v / (1.0f + expf(-v));
}

// ---- Stage 1: fp16 feature field: field[z][y][x][c][t], t in [0,12) -------
// t=0: silu(v); t=1..8: B-spline bases; t=9..11: zero padding.
__global__ void precompute_field(const float* __restrict__ x,
                                 _Float16* __restrict__ field) {
    int idx = blockIdx.x * blockDim.x + threadIdx.x;  // (voxel, c)
    if (idx >= NVOX * IN_CH) return;
    int c   = idx & 7;
    int vox = idx >> 3;
    int xp = vox % PDIM;
    int t2 = vox / PDIM;
    int yp = t2 % PDIM;
    int zp = t2 / PDIM;
    float v = 0.0f;
    if (xp >= 1 && xp <= DIM && yp >= 1 && yp <= DIM && zp >= 1 && zp <= DIM)
        v = x[((c * DIM + (zp - 1)) * DIM + (yp - 1)) * DIM + (xp - 1)];
    float b[11];
    eval_bases(v, b);
    __align__(8) _Float16 h[TPAD];
    h[0] = (_Float16)silu(v);
    #pragma unroll
    for (int j = 0; j < NBASES; ++j) h[1 + j] = (_Float16)b[j];
    h[9] = (_Float16)0.f; h[10] = (_Float16)0.f; h[11] = (_Float16)0.f;
    uint2* d = (uint2*)(field + (size_t)idx * TPAD);   // 24 B, 8-aligned
    d[0] = *(uint2*)&h[0];
    d[1] = *(uint2*)&h[4];
    d[2] = *(uint2*)&h[8];
}

// ---- Stage 1b: weights Wt[(tap*3+q)*16 + o][32] fp16 ----------------------
// k = q*32 + kl (0..95), c = k/12, t = k%12; t==0 -> base, 1..8 -> spline*scaler.
__global__ void prep_weights(const float* __restrict__ bw,   // [16][216]
                             const float* __restrict__ sw,   // [16][216][8]
                             const float* __restrict__ sc,   // [16][216]
                             _Float16* __restrict__ Wt) {
    int id = blockIdx.x * blockDim.x + threadIdx.x;
    if (id >= 27 * 3 * 16 * 32) return;
    int kl  = id & 31;
    int o   = (id >> 5) & 15;
    int tq  = id >> 9;          // tap*3 + q
    int q   = tq % 3;
    int tap = tq / 3;
    int k = q * 32 + kl;        // 0..95
    int cch = k / TPAD, t = k % TPAD;
    float val = 0.0f;
    if (t < 9) {
        int wi = o * NF + (cch * 27 + tap);
        val = (t == 0) ? bw[wi] : sw[(size_t)wi * NBASES + (t - 1)] * sc[wi];
    }
    Wt[id] = (_Float16)val;
}

// ---- Stage 2: implicit-GEMM conv via MFMA ---------------------------------
// Block: 256 thr = 4 waves. Tile: 16(x) x 2(y) x 2(z) positions.
// LDS: halo field 18 x 4 x 4 voxels * 192 B = 55,296 B.
// Wave w -> (yw,zw); 81 mfma_f32_16x16x32_f16: a=W rows (o), b=field cols (p).
__global__ __launch_bounds__(256) void conv_mfma(const _Float16* __restrict__ field,
                                                 const _Float16* __restrict__ Wt,
                                                 float* __restrict__ out) {
    __shared__ __align__(16) _Float16 lf[288 * KVOX];   // 27648 halves
    int bx = blockIdx.x;
    int x0 = (bx & 1) * 16;
    int y0 = ((bx >> 1) & 15) * 2;
    int z0 = (bx >> 5) * 2;
    int tid = threadIdx.x;

    // stage halo: 16 rows (z'*4+y') of 18 voxels = 3456 B each -> 3456 16B chunks
    for (int ch = tid; ch < 3456; ch += 256) {
        int row = ch / 216;          // z'*4 + y'
        int off = ch % 216;          // 16B units within row
        int zp = z0 + (row >> 2), yp = y0 + (row & 3);
        const float4* g = (const float4*)(field + ((size_t)(zp * PDIM + yp) * PDIM + x0) * KVOX) + off;
        *(float4*)(lf + ch * 8) = *g;
    }
    __syncthreads();

    int lane = tid & 63;
    int w    = tid >> 6;
    int yw = w & 1, zw = w >> 1;
    int po = lane & 15;      // a: out-channel row; b: position col
    int kq = lane >> 4;      // K sub-chunk (8 halves each)
    f32x4 acc = {0.f, 0.f, 0.f, 0.f};

    #pragma unroll
    for (int kd = 0; kd < 3; ++kd) {
        #pragma unroll
        for (int kh = 0; kh < 3; ++kh) {
            const _Float16* lrow = lf + ((zw + kd) * 4 + (yw + kh)) * (18 * KVOX);
            #pragma unroll
            for (int kw = 0; kw < 3; ++kw) {
                #pragma unroll
                for (int q = 0; q < 3; ++q) {
                    int tap = (kd * 3 + kh) * 3 + kw;
                    half8 a = *(const half8*)(Wt + ((tap * 3 + q) * 16 + po) * 32 + kq * 8);
                    half8 b = *(const half8*)(lrow + (po + kw) * KVOX + q * 32 + kq * 8);
                    acc = __builtin_amdgcn_mfma_f32_16x16x32_f16(a, b, acc, 0, 0, 0);
                }
            }
        }
    }

    int pos = ((z0 + zw) * 32 + (y0 + yw)) * 32 + x0 + po;
    #pragma unroll
    for (int r = 0; r < 4; ++r)
        out[(size_t)(kq * 4 + r) * LTOT + pos] = acc[r];
}

// ---------------- Fallback: fully fused (no workspace needed) ---------------
__global__ __launch_bounds__(64) void fused_kernel(const float* __restrict__ x,
                                                   const float* __restrict__ bw,
                                                   const float* __restrict__ sw,
                                                   const float* __restrict__ sc,
                                                   float* __restrict__ out) {
    int p = blockIdx.x * 64 + threadIdx.x;
    int xo = p & 31;
    int yo = (p >> 5) & 31;
    int zo = p >> 10;
    float acc[OUT_CH];
    #pragma unroll
    for (int o = 0; o < OUT_CH; ++o) acc[o] = 0.0f;
    for (int c = 0; c < IN_CH; ++c)
        for (int kd = 0; kd < 3; ++kd)
            for (int kh = 0; kh < 3; ++kh)
                for (int kw = 0; kw < 3; ++kw) {
                    int zi = zo + kd - 1, yi = yo + kh - 1, xi = xo + kw - 1;
                    float v = 0.0f;
                    if (zi >= 0 && zi < DIM && yi >= 0 && yi < DIM && xi >= 0 && xi < DIM)
                        v = x[((c * DIM + zi) * DIM + yi) * DIM + xi];
                    float b[11];
                    eval_bases(v, b);
                    float s = silu(v);
                    int i = c * 27 + kd * 9 + kh * 3 + kw;
                    #pragma unroll
                    for (int o = 0; o < OUT_CH; ++o) {
                        int wi = o * NF + i;
                        float dot = 0.0f;
                        #pragma unroll
                        for (int j = 0; j < NBASES; ++j)
                            dot += b[j] * sw[(size_t)wi * NBASES + j];
                        acc[o] += s * bw[wi] + sc[wi] * dot;
                    }
                }
    #pragma unroll
    for (int o = 0; o < OUT_CH; ++o)
        out[(size_t)o * LTOT + p] = acc[o];
}

extern "C" void kernel_launch(void* const* d_in, const int* in_sizes, int n_in,
                              void* d_out, int out_size, void* d_ws, size_t ws_size,
                              hipStream_t stream) {
    const float* x  = (const float*)d_in[0];
    const float* bw = (const float*)d_in[1];
    const float* sw = (const float*)d_in[2];
    const float* sc = (const float*)d_in[3];
    float* out = (float*)d_out;

    const size_t F_bytes = (size_t)NVOX * IN_CH * TPAD * 2;   // 7,546,368
    const size_t W_bytes = (size_t)27 * 3 * 16 * 32 * 2;      // 82,944
    const size_t F_off = 0;
    const size_t W_off = F_off + F_bytes;                      // 16B aligned
    const size_t need  = W_off + W_bytes;

    if (ws_size >= need) {
        _Float16* field = (_Float16*)((char*)d_ws + F_off);
        _Float16* Wt    = (_Float16*)((char*)d_ws + W_off);
        const int total1 = NVOX * IN_CH;
        precompute_field<<<(total1 + 255) / 256, 256, 0, stream>>>(x, field);
        prep_weights<<<(27 * 3 * 16 * 32 + 255) / 256, 256, 0, stream>>>(bw, sw, sc, Wt);
        conv_mfma<<<512, 256, 0, stream>>>(field, Wt, out);
    } else {
        fused_kernel<<<512, 64, 0, stream>>>(x, bw, sw, sc, out);
    }
}